// Round 18
// baseline (442.955 us; speedup 1.0000x reference)
//
#include <hip/hip_runtime.h>
#include <hip/hip_bf16.h>
#include <math.h>

#define B_SZ   256
#define D_DIM  256
#define C_DIM  64
#define N_CAND 200000
#define K_TOP  5
#define CH32   32
#define CH32_SH 8192                          // shorts per 32-cand chunk (16KB)
#define QTILE_SH 16384                        // shorts per 64-query tile (32KB)
#define NCH32  (N_CAND / CH32)                // 6250 chunks (exact)
#define CMSTR  6256                           // cmax row stride (16B-aligned, padded)
#define NCHJ1  25                             // chunks/job pass 1 -> 250 blocks
#define NCHJ2  74                             // chunks/job pass 2 -> 85 jobs x 3 qtiles = 255 blocks
#define S1     ((NCH32 + NCHJ1 - 1) / NCHJ1)  // 250
#define S2     ((NCH32 + NCHJ2 - 1) / NCHJ2)  // 85 (last job 34 chunks)
#define MAXC   192                            // max rescored chunks per query

typedef short bf16x8 __attribute__((ext_vector_type(8)));
typedef float f32x16 __attribute__((ext_vector_type(16)));
typedef unsigned short u16x8 __attribute__((ext_vector_type(8)));

__device__ __forceinline__ bool better(float v1, int i1, float v2, int i2) {
    return (v1 > v2) || (v1 == v2 && i1 < i2);
}

__device__ __forceinline__ void insert6f(float* lv, int* li, float v, int idx) {
    if (better(v, idx, lv[5], li[5])) {
        lv[5] = v; li[5] = idx;
        #pragma unroll
        for (int k = 5; k > 0; --k) {
            if (better(lv[k], li[k], lv[k - 1], li[k - 1])) {
                float tv = lv[k]; lv[k] = lv[k - 1]; lv[k - 1] = tv;
                int   ti = li[k]; li[k] = li[k - 1]; li[k - 1] = ti;
            }
        }
    }
}

__device__ __forceinline__ void merge6(const float* av, const int* ai,
                                       const float* bv, const int* bi,
                                       float* ov, int* oi) {
    int ia = 0, ib = 0;
    #pragma unroll
    for (int k = 0; k < 6; ++k) {
        bool ta;
        if (ia >= 6)      ta = false;
        else if (ib >= 6) ta = true;
        else              ta = better(av[ia], ai[ia], bv[ib], bi[ib]);
        if (ta) { ov[k] = av[ia]; oi[k] = ai[ia]; ++ia; }
        else    { ov[k] = bv[ib]; oi[k] = bi[ib]; ++ib; }
    }
}

__device__ __forceinline__ unsigned short bf16rne(float x) {
    unsigned int u = __float_as_uint(x);
    unsigned int r = u + 0x7fffu + ((u >> 16) & 1u);
    return (unsigned short)(r >> 16);
}

__device__ __forceinline__ float bf16f(unsigned short h) {
    return __uint_as_float(((unsigned)h) << 16);
}

__device__ __forceinline__ u16x8 pack8(float4 a, float4 b) {
    u16x8 h;
    h[0] = bf16rne(a.x); h[1] = bf16rne(a.y); h[2] = bf16rne(a.z); h[3] = bf16rne(a.w);
    h[4] = bf16rne(b.x); h[5] = bf16rne(b.y); h[6] = bf16rne(b.z); h[7] = bf16rne(b.w);
    return h;
}

__global__ void k_init(int* pos_of, float* accp) {
    int i = blockIdx.x * 256 + threadIdx.x;
    if (i < N_CAND) pos_of[i] = -1;
    if (i == 0) accp[0] = 0.f;
}

__global__ void k_scatter(const int* __restrict__ trg, int* __restrict__ pos_of) {
    int j = threadIdx.x;
    atomicMax(&pos_of[trg[j]], j);
}

__global__ __launch_bounds__(256) void k_prep(const float* __restrict__ features,
                                              const float* __restrict__ W,
                                              const float* __restrict__ bias,
                                              float* __restrict__ f_norm,
                                              float* __restrict__ softm) {
    int b = blockIdx.x, t = threadIdx.x;
    __shared__ float row[256];
    __shared__ float red[256];
    float x = features[b * D_DIM + t];
    row[t] = x; red[t] = x * x;
    __syncthreads();
    for (int s = 128; s > 0; s >>= 1) {
        if (t < s) red[t] += red[t + s];
        __syncthreads();
    }
    float nrm = fmaxf(sqrtf(red[0]), 1e-12f);
    f_norm[b * D_DIM + t] = x / nrm;
    if (t < C_DIM) {
        float acc = bias[t];
        for (int d = 0; d < D_DIM; ++d) acc = fmaf(row[d], W[d * C_DIM + t], acc);
        float mx = acc;
        for (int off = 32; off > 0; off >>= 1) mx = fmaxf(mx, __shfl_xor(mx, off, 64));
        float e = expf(acc - mx);
        float ssum = e;
        for (int off = 32; off > 0; off >>= 1) ssum += __shfl_xor(ssum, off, 64);
        softm[b * C_DIM + t] = e / ssum;
    }
}

// one-shot: fea_bank (with f_norm substitution) -> pre-permuted bf16 32-cand chunks
__global__ __launch_bounds__(256) void k_convert(const float* __restrict__ fea_bank,
                                                 const float* __restrict__ f_norm,
                                                 const int* __restrict__ pos_of,
                                                 short* __restrict__ bank) {
    int cc = blockIdx.x, t = threadIdx.x;
    int r = t >> 2, q4 = t & 3;
    int n = cc * 64 + r;
    int p = pos_of[n];
    const float* src = (p >= 0) ? (f_norm + (size_t)p * D_DIM)
                                : (fea_bank + (size_t)n * D_DIM);
    short* dst = bank + (size_t)(cc * 2 + (r >> 5)) * CH32_SH;
    int rl = r & 31;
    #pragma unroll
    for (int i = 0; i < 8; ++i) {
        int kk = i * 32 + q4 * 8;
        float4 a = *(const float4*)(src + kk);
        float4 b = *(const float4*)(src + kk + 4);
        int e = ((kk >> 4) * 64) + (((kk >> 3) & 1) * 32) + rl;
        *(u16x8*)(dst + (size_t)e * 8) = pack8(a, b);
    }
}

// permute query rows into fragment-order tiles AND plain bf16 rows
__global__ __launch_bounds__(256) void k_permq(const float* __restrict__ rows,
                                               const float* __restrict__ fea_bank,
                                               const int* __restrict__ idx,
                                               const int* __restrict__ pos_of,
                                               short* __restrict__ dst,
                                               unsigned short* __restrict__ qplain) {
    int tile = blockIdx.x, t = threadIdx.x;
    int r = t >> 2, q4 = t & 3;
    const float* src;
    if (idx) {
        int n = idx[tile * 64 + r];
        int p = pos_of[n];
        src = (p >= 0) ? (rows + (size_t)p * D_DIM) : (fea_bank + (size_t)n * D_DIM);
    } else {
        src = rows + (size_t)(tile * 64 + r) * D_DIM;
    }
    short* d = dst + (size_t)tile * QTILE_SH;
    unsigned short* qp = qplain + (size_t)(tile * 64 + r) * D_DIM;
    #pragma unroll
    for (int i = 0; i < 8; ++i) {
        int kk = i * 32 + q4 * 8;
        float4 a = *(const float4*)(src + kk);
        float4 b = *(const float4*)(src + kk + 4);
        u16x8 h = pack8(a, b);
        int e = ((kk >> 4) * 128) + ((r >> 5) * 64) + (((kk >> 3) & 1) * 32) + (r & 31);
        *(u16x8*)(d + (size_t)e * 8) = h;
        *(u16x8*)(qp + kk) = h;
    }
}

// PHASE 1: MFMA distance + per-(query,chunk) MAX.
// 512 threads = 8 waves, ONE block/CU (launch_bounds(512,2) -> VGPR cap 256):
// each wave holds 64 queries TRULY resident (128 VGPR, s_nop-pinned).
// 3-buffer ring, counted vmcnt (2 loads/wave/chunk; 2 chunks in flight).
// cmaxbuf 8 chunks deep, flushed with lgkmcnt-only barrier (no vmcnt drain).
// LDS = 48KB ring + 8KB cmaxbuf = 56KB.
__global__ __launch_bounds__(512, 2) void dist_max(const short* __restrict__ qbf,
                                                   const short* __restrict__ bank,
                                                   unsigned short* __restrict__ cmax,
                                                   int nqt, int swz,
                                                   int S, int nchj, int maxtile) {
    __shared__ __align__(16) short sbuf[3 * CH32_SH];        // 48 KB ring
    __shared__ unsigned short cmaxbuf[8 * 512];              // 8 KB [ch&7][qrow]

    int slab, qt;
    if (swz) {
        int bid = blockIdx.x;
        int xcd = bid & 7;
        int rem = bid >> 3;
        qt = rem % nqt;
        slab = (rem / nqt) * 8 + xcd;
        if (slab >= S) return;
    } else {
        slab = blockIdx.x;
        qt = blockIdx.y;
    }
    const int cfirst = slab * nchj;
    int nch = NCH32 - cfirst; if (nch > nchj) nch = nchj;

    const int t   = threadIdx.x;
    const int w   = t >> 6;
    const int l   = t & 63;
    const int khv = l >> 5;
    const int col = l & 31;

    // ---- B-frags: this wave's 64 queries, TRULY resident ----
    int ti = qt * 8 + w; if (ti > maxtile) ti = maxtile;   // ragged tail: duplicate work
    const short* qtile = qbf + (size_t)ti * QTILE_SH;
    bf16x8 bfr0[16], bfr1[16];
    #pragma unroll
    for (int ks = 0; ks < 16; ++ks) {
        bfr0[ks] = *(const bf16x8*)(qtile + (size_t)(ks * 128      + l) * 8);
        bfr1[ks] = *(const bf16x8*)(qtile + (size_t)(ks * 128 + 64 + l) * 8);
    }
    // pin with a REAL instruction: cannot be deleted or rematerialized
    #pragma unroll
    for (int ks = 0; ks < 16; ++ks) {
        asm volatile("s_nop 0" : "+v"(bfr0[ks]));
        asm volatile("s_nop 0" : "+v"(bfr1[ks]));
    }

    const short* sbase = bank + (size_t)cfirst * CH32_SH;

    // ---- prologue: issue chunks 0,1 (2 calls/wave each) ----
    #pragma unroll
    for (int c = 0; c < 2; ++c) {
        const short* g = sbase + (size_t)c * CH32_SH;
        short* lbase = sbuf + (size_t)c * CH32_SH;
        #pragma unroll
        for (int i = 0; i < 2; ++i) {
            const short* gp = g + (size_t)(i * 512 + t) * 8;
            short* lp = lbase + (size_t)(i * 512 + w * 64) * 8;
            __builtin_amdgcn_global_load_lds(
                (const __attribute__((address_space(1))) void*)gp,
                (__attribute__((address_space(3))) void*)lp, 16, 0, 0);
        }
    }

    for (int ch = 0; ch < nch; ++ch) {
        int ahead = nch - 1 - ch;
        if (ahead >= 2)      asm volatile("s_waitcnt vmcnt(4)" ::: "memory");
        else if (ahead == 1) asm volatile("s_waitcnt vmcnt(2)" ::: "memory");
        else                 asm volatile("s_waitcnt vmcnt(0)" ::: "memory");
        __builtin_amdgcn_s_barrier();
        __builtin_amdgcn_sched_barrier(0);

        const short* cb = sbuf + (size_t)(ch % 3) * CH32_SH;

        f32x16 a0 = {}, a1 = {};
        __builtin_amdgcn_s_setprio(1);
        #pragma unroll
        for (int ks = 0; ks < 16; ++ks) {
            bf16x8 fa = *(const bf16x8*)(cb + (size_t)(ks * 64 + l) * 8);
            a0 = __builtin_amdgcn_mfma_f32_32x32x16_bf16(fa, bfr0[ks], a0, 0, 0, 0);
            a1 = __builtin_amdgcn_mfma_f32_32x32x16_bf16(fa, bfr1[ks], a1, 0, 0, 0);
        }
        __builtin_amdgcn_s_setprio(0);

        float m0 = a0[0], m1 = a1[0];
        #pragma unroll
        for (int r = 1; r < 16; ++r) { m0 = fmaxf(m0, a0[r]); m1 = fmaxf(m1, a1[r]); }
        m0 = fmaxf(m0, __shfl_xor(m0, 32, 64));
        m1 = fmaxf(m1, __shfl_xor(m1, 32, 64));
        if (khv == 0) {
            cmaxbuf[(ch & 7) * 512 + w * 64 + col]      = bf16rne(m0);
            cmaxbuf[(ch & 7) * 512 + w * 64 + 32 + col] = bf16rne(m1);
        }

        if (ch + 2 < nch) {
            const short* g = sbase + (size_t)(ch + 2) * CH32_SH;
            short* lbase = sbuf + (size_t)((ch + 2) % 3) * CH32_SH;
            #pragma unroll
            for (int i = 0; i < 2; ++i) {
                const short* gp = g + (size_t)(i * 512 + t) * 8;
                short* lp = lbase + (size_t)(i * 512 + w * 64) * 8;
                __builtin_amdgcn_global_load_lds(
                    (const __attribute__((address_space(1))) void*)gp,
                    (__attribute__((address_space(3))) void*)lp, 16, 0, 0);
            }
        }

        if ((ch & 7) == 7 || ch == nch - 1) {
            // flush cmaxbuf rows [ch&~7 .. ch] -- LDS-only sync (keep vmem in flight)
            asm volatile("s_waitcnt lgkmcnt(0)" ::: "memory");
            __builtin_amdgcn_s_barrier();
            int chbase = ch & ~7;
            int cnt = ch - chbase + 1;
            int tig = qt * 8 + (t >> 6); if (tig > maxtile) tig = maxtile;
            int gq = tig * 64 + (t & 63);
            size_t gbase = (size_t)gq * CMSTR + cfirst + chbase;
            if (cnt == 8) {
                u16x8 h;
                #pragma unroll
                for (int i = 0; i < 8; ++i) h[i] = cmaxbuf[i * 512 + t];
                *(u16x8*)(cmax + gbase) = h;
            } else {
                for (int k = 0; k < cnt; ++k) cmax[gbase + k] = cmaxbuf[k * 512 + t];
            }
            if (ch == nch - 1) {
                // pad tail rows so vector scans in k_select are exact
                int cend = (cfirst + nchj >= NCH32) ? (CMSTR - cfirst) : nchj;
                for (int cp = nch; cp < cend; ++cp)
                    cmax[(size_t)gq * CMSTR + cfirst + cp] = 0xFF7F;
            }
            __builtin_amdgcn_s_barrier();   // cmaxbuf safe to reuse next chunk
        }
    }
}

// PHASE 2: per query: tau = 6th-best chunk-max; rescore chunks >= tau - 6e-3
// from the bf16 bank; exact top-6 -> write ranks 1..5.
__global__ __launch_bounds__(256) void k_select(const unsigned short* __restrict__ cmax,
                                                const unsigned short* __restrict__ qplain,
                                                const short* __restrict__ bank,
                                                int* __restrict__ out_idx) {
    int q = blockIdx.x, t = threadIdx.x;
    __shared__ float sv[256][6];
    __shared__ int   si[256][6];
    __shared__ float qrow[256];
    __shared__ int cnt;
    __shared__ int list[MAXC];

    const unsigned short* row = cmax + (size_t)q * CMSTR;

    float lv[6]; int li[6];
    #pragma unroll
    for (int k = 0; k < 6; ++k) { lv[k] = -3.4e38f; li[k] = 0x7fffffff; }
    for (int c0 = t * 8; c0 < CMSTR; c0 += 2048) {
        u16x8 h = *(const u16x8*)(row + c0);
        float m8 = bf16f(h[0]);
        #pragma unroll
        for (int i = 1; i < 8; ++i) m8 = fmaxf(m8, bf16f(h[i]));
        if (better(m8, c0, lv[5], li[5])) {
            #pragma unroll
            for (int i = 0; i < 8; ++i) {
                int c = c0 + i;
                if (c < NCH32) insert6f(lv, li, bf16f(h[i]), c);
            }
        }
    }
    #pragma unroll
    for (int k = 0; k < 6; ++k) { sv[t][k] = lv[k]; si[t][k] = li[k]; }
    if (t == 0) cnt = 0;
    __syncthreads();
    for (int w = 128; w >= 1; w >>= 1) {
        if (t < w) {
            float ov[6]; int oi[6];
            merge6(sv[t], si[t], sv[t + w], si[t + w], ov, oi);
            #pragma unroll
            for (int k = 0; k < 6; ++k) { sv[t][k] = ov[k]; si[t][k] = oi[k]; }
        }
        __syncthreads();
    }
    float tauM = sv[0][5] - 6e-3f;
    __syncthreads();

    for (int c0 = t * 8; c0 < CMSTR; c0 += 2048) {
        u16x8 h = *(const u16x8*)(row + c0);
        float m8 = bf16f(h[0]);
        #pragma unroll
        for (int i = 1; i < 8; ++i) m8 = fmaxf(m8, bf16f(h[i]));
        if (m8 >= tauM) {
            #pragma unroll
            for (int i = 0; i < 8; ++i) {
                int c = c0 + i;
                if (c < NCH32 && bf16f(h[i]) >= tauM) {
                    int k = atomicAdd(&cnt, 1);
                    if (k < MAXC) list[k] = c;
                }
            }
        }
    }
    qrow[t] = bf16f(qplain[(size_t)q * D_DIM + t]);
    __syncthreads();
    int nc = cnt < MAXC ? cnt : MAXC;

    float bv[6]; int bi[6];
    #pragma unroll
    for (int k = 0; k < 6; ++k) { bv[k] = -3.4e38f; bi[k] = 0x7fffffff; }
    const int cand = t >> 3, j = t & 7;
    for (int ci = 0; ci < nc; ++ci) {
        int c = list[ci];
        const short* cb = bank + (size_t)c * CH32_SH;
        u16x8 h0 = *(const u16x8*)(cb + (size_t)(128 * j +  0 + cand) * 8);
        u16x8 h1 = *(const u16x8*)(cb + (size_t)(128 * j + 32 + cand) * 8);
        u16x8 h2 = *(const u16x8*)(cb + (size_t)(128 * j + 64 + cand) * 8);
        u16x8 h3 = *(const u16x8*)(cb + (size_t)(128 * j + 96 + cand) * 8);
        int d0 = j * 32;
        float acc = 0.f;
        #pragma unroll
        for (int d = 0; d < 8; ++d) {
            acc = fmaf(bf16f(h0[d]), qrow[d0 + d], acc);
            acc = fmaf(bf16f(h1[d]), qrow[d0 + 8 + d], acc);
            acc = fmaf(bf16f(h2[d]), qrow[d0 + 16 + d], acc);
            acc = fmaf(bf16f(h3[d]), qrow[d0 + 24 + d], acc);
        }
        acc += __shfl_down(acc, 4, 8);
        acc += __shfl_down(acc, 2, 8);
        acc += __shfl_down(acc, 1, 8);
        if (j == 0) insert6f(bv, bi, acc, c * CH32 + cand);
    }

    #pragma unroll
    for (int k = 0; k < 6; ++k) { sv[t][k] = bv[k]; si[t][k] = bi[k]; }
    __syncthreads();
    for (int w = 128; w >= 1; w >>= 1) {
        if (t < w) {
            float ov[6]; int oi[6];
            merge6(sv[t], si[t], sv[t + w], si[t + w], ov, oi);
            #pragma unroll
            for (int k = 0; k < 6; ++k) { sv[t][k] = ov[k]; si[t][k] = oi[k]; }
        }
        __syncthreads();
    }
    if (t == 0) {
        for (int k = 1; k < 6; ++k) out_idx[q * K_TOP + k - 1] = si[0][k];
    }
}

__global__ void k_loss(const float* __restrict__ softm, const float* __restrict__ score_bank,
                       const int* __restrict__ pos_of, const int* __restrict__ idx_near,
                       const int* __restrict__ idx_nn, const int* __restrict__ trg,
                       float* accp) {
    int b = blockIdx.x, c = threadIdx.x;   // 64 threads
    float p_bc = softm[b * C_DIM + c];
    float part = 0.f;
    for (int k = 0; k < K_TOP; ++k) {
        for (int j = 0; j < K_TOP; ++j) {
            int n = idx_nn[(b * K_TOP + k) * K_TOP + j];
            int p = pos_of[n];
            const float* srow = (p >= 0) ? (softm + (size_t)p * C_DIM)
                                         : (score_bank + (size_t)n * C_DIM);
            float s = srow[c];
            float v = s * (logf(s) - p_bc);
            for (int off = 32; off > 0; off >>= 1) v += __shfl_down(v, off, 64);
            if (c == 0) part += 0.1f * v;
        }
    }
    for (int k = 0; k < K_TOP; ++k) {
        int n = idx_near[b * K_TOP + k];
        int p = pos_of[n];
        const float* srow = (p >= 0) ? (softm + (size_t)p * C_DIM)
                                     : (score_bank + (size_t)n * C_DIM);
        float s = srow[c];
        float v = s * (logf(s) - p_bc);
        for (int off = 32; off > 0; off >>= 1) v += __shfl_down(v, off, 64);
        if (c == 0) {
            int m = 0;
            for (int j = 0; j < K_TOP; ++j)
                m += (idx_nn[(b * K_TOP + k) * K_TOP + j] == trg[b]) ? 1 : 0;
            float w = (m > 0) ? (float)m : 0.1f;
            part += w * v;
        }
    }
    if (c == 0) atomicAdd(accp, part * (1.0f / (float)B_SZ));
}

__global__ void k_final(const float* __restrict__ softm, const float* __restrict__ accp,
                        float* __restrict__ out) {
    int c = threadIdx.x;   // 64
    float m = 0.f;
    for (int b = 0; b < B_SZ; ++b) m += softm[b * C_DIM + c];
    m *= (1.0f / (float)B_SZ);
    float g = m * logf(m + 1e-5f);
    for (int off = 32; off > 0; off >>= 1) g += __shfl_down(g, off, 64);
    if (c == 0) out[0] = accp[0] + g;
}

extern "C" void kernel_launch(void* const* d_in, const int* in_sizes, int n_in,
                              void* d_out, int out_size, void* d_ws, size_t ws_size,
                              hipStream_t stream) {
    const float* features   = (const float*)d_in[0];
    const float* W          = (const float*)d_in[1];
    const float* bias       = (const float*)d_in[2];
    const float* fea_bank   = (const float*)d_in[3];
    const float* score_bank = (const float*)d_in[4];
    const int*   trg        = (const int*)d_in[5];
    float* out = (float*)d_out;

    char* ws = (char*)d_ws;
    size_t off = 0;
    auto alloc = [&](size_t bytes) -> void* {
        void* p = ws + off;
        off = (off + bytes + 255) & ~(size_t)255;
        return p;
    };
    short* bankbf   = (short*)alloc((size_t)NCH32 * CH32_SH * 2);            // 102.4 MB
    short* q1bf     = (short*)alloc((size_t)(B_SZ / 64) * QTILE_SH * 2);
    short* q2bf     = (short*)alloc((size_t)(B_SZ * K_TOP / 64) * QTILE_SH * 2);
    unsigned short* qplain1 = (unsigned short*)alloc((size_t)B_SZ * D_DIM * 2);
    unsigned short* qplain2 = (unsigned short*)alloc((size_t)B_SZ * K_TOP * D_DIM * 2);
    float* f_norm   = (float*)alloc((size_t)B_SZ * D_DIM * 4);
    float* softm    = (float*)alloc((size_t)B_SZ * C_DIM * 4);
    int*   pos_of   = (int*)alloc((size_t)N_CAND * 4);
    float* accp     = (float*)alloc(4);
    int*   idx_near = (int*)alloc((size_t)B_SZ * K_TOP * 4);
    int*   idx_nn   = (int*)alloc((size_t)B_SZ * K_TOP * K_TOP * 4);
    unsigned short* cmax1 = (unsigned short*)alloc((size_t)B_SZ * CMSTR * 2);
    unsigned short* cmax2 = (unsigned short*)alloc((size_t)B_SZ * K_TOP * CMSTR * 2);

    k_init<<<dim3((N_CAND + 255) / 256), dim3(256), 0, stream>>>(pos_of, accp);
    k_scatter<<<dim3(1), dim3(256), 0, stream>>>(trg, pos_of);
    k_prep<<<dim3(B_SZ), dim3(256), 0, stream>>>(features, W, bias, f_norm, softm);

    k_convert<<<dim3(NCH32 / 2), dim3(256), 0, stream>>>(fea_bank, f_norm, pos_of, bankbf);
    k_permq<<<dim3(B_SZ / 64), dim3(256), 0, stream>>>(
        f_norm, fea_bank, nullptr, pos_of, q1bf, qplain1);

    // pass 1 phase 1: 256 queries (4 tiles, waves 4-7 duplicate); 25-chunk jobs, 250 blocks
    dist_max<<<dim3(S1, 1), dim3(512), 0, stream>>>(
        q1bf, bankbf, cmax1, 1, 0, S1, NCHJ1, 3);
    k_select<<<dim3(B_SZ), dim3(256), 0, stream>>>(cmax1, qplain1, bankbf, idx_near);

    k_permq<<<dim3(B_SZ * K_TOP / 64), dim3(256), 0, stream>>>(
        f_norm, fea_bank, idx_near, pos_of, q2bf, qplain2);

    // pass 2 phase 1: 1280 queries = 3 qtiles of 512 (ragged -> clamp); 74-chunk jobs
    {
        int nqt = 3;
        int nsg = (S2 + 7) / 8;                   // 11
        dist_max<<<dim3(nsg * 8 * nqt), dim3(512), 0, stream>>>(
            q2bf, bankbf, cmax2, nqt, 1, S2, NCHJ2, 19);
    }
    k_select<<<dim3(B_SZ * K_TOP), dim3(256), 0, stream>>>(cmax2, qplain2, bankbf, idx_nn);

    k_loss<<<dim3(B_SZ), dim3(64), 0, stream>>>(softm, score_bank, pos_of, idx_near, idx_nn, trg, accp);
    k_final<<<dim3(1), dim3(64), 0, stream>>>(softm, accp, out);
}

// Round 19
// 316.891 us; speedup vs baseline: 1.3978x; 1.3978x over previous
//
#include <hip/hip_runtime.h>
#include <hip/hip_bf16.h>
#include <math.h>

#define B_SZ   256
#define D_DIM  256
#define C_DIM  64
#define N_CAND 200000
#define K_TOP  5
#define CH32   32
#define CH32_SH 8192                          // shorts per 32-cand chunk (16KB)
#define QTILE_SH 16384                        // shorts per 64-query tile (32KB)
#define NCH32  (N_CAND / CH32)                // 6250 chunks (exact)
#define CMSTR  6256                           // cmax row stride (16B-aligned, padded)
#define NCHJ1  16                             // chunks/job pass 1
#define NCHJ2  32                             // chunks/job pass 2
#define S1     ((NCH32 + NCHJ1 - 1) / NCHJ1)  // 391 (last job 10 chunks)
#define S2     ((NCH32 + NCHJ2 - 1) / NCHJ2)  // 196 (last job 10 chunks)
#define MAXC   192                            // max rescored chunks per query

typedef short bf16x8 __attribute__((ext_vector_type(8)));
typedef float f32x16 __attribute__((ext_vector_type(16)));
typedef unsigned short u16x8 __attribute__((ext_vector_type(8)));

__device__ __forceinline__ bool better(float v1, int i1, float v2, int i2) {
    return (v1 > v2) || (v1 == v2 && i1 < i2);
}

__device__ __forceinline__ void insert6f(float* lv, int* li, float v, int idx) {
    if (better(v, idx, lv[5], li[5])) {
        lv[5] = v; li[5] = idx;
        #pragma unroll
        for (int k = 5; k > 0; --k) {
            if (better(lv[k], li[k], lv[k - 1], li[k - 1])) {
                float tv = lv[k]; lv[k] = lv[k - 1]; lv[k - 1] = tv;
                int   ti = li[k]; li[k] = li[k - 1]; li[k - 1] = ti;
            }
        }
    }
}

__device__ __forceinline__ void merge6(const float* av, const int* ai,
                                       const float* bv, const int* bi,
                                       float* ov, int* oi) {
    int ia = 0, ib = 0;
    #pragma unroll
    for (int k = 0; k < 6; ++k) {
        bool ta;
        if (ia >= 6)      ta = false;
        else if (ib >= 6) ta = true;
        else              ta = better(av[ia], ai[ia], bv[ib], bi[ib]);
        if (ta) { ov[k] = av[ia]; oi[k] = ai[ia]; ++ia; }
        else    { ov[k] = bv[ib]; oi[k] = bi[ib]; ++ib; }
    }
}

__device__ __forceinline__ unsigned short bf16rne(float x) {
    unsigned int u = __float_as_uint(x);
    unsigned int r = u + 0x7fffu + ((u >> 16) & 1u);
    return (unsigned short)(r >> 16);
}

__device__ __forceinline__ float bf16f(unsigned short h) {
    return __uint_as_float(((unsigned)h) << 16);
}

__device__ __forceinline__ u16x8 pack8(float4 a, float4 b) {
    u16x8 h;
    h[0] = bf16rne(a.x); h[1] = bf16rne(a.y); h[2] = bf16rne(a.z); h[3] = bf16rne(a.w);
    h[4] = bf16rne(b.x); h[5] = bf16rne(b.y); h[6] = bf16rne(b.z); h[7] = bf16rne(b.w);
    return h;
}

__global__ void k_init(int* pos_of, float* accp) {
    int i = blockIdx.x * 256 + threadIdx.x;
    if (i < N_CAND) pos_of[i] = -1;
    if (i == 0) accp[0] = 0.f;
}

__global__ void k_scatter(const int* __restrict__ trg, int* __restrict__ pos_of) {
    int j = threadIdx.x;
    atomicMax(&pos_of[trg[j]], j);
}

__global__ __launch_bounds__(256) void k_prep(const float* __restrict__ features,
                                              const float* __restrict__ W,
                                              const float* __restrict__ bias,
                                              float* __restrict__ f_norm,
                                              float* __restrict__ softm) {
    int b = blockIdx.x, t = threadIdx.x;
    __shared__ float row[256];
    __shared__ float red[256];
    float x = features[b * D_DIM + t];
    row[t] = x; red[t] = x * x;
    __syncthreads();
    for (int s = 128; s > 0; s >>= 1) {
        if (t < s) red[t] += red[t + s];
        __syncthreads();
    }
    float nrm = fmaxf(sqrtf(red[0]), 1e-12f);
    f_norm[b * D_DIM + t] = x / nrm;
    if (t < C_DIM) {
        float acc = bias[t];
        for (int d = 0; d < D_DIM; ++d) acc = fmaf(row[d], W[d * C_DIM + t], acc);
        float mx = acc;
        for (int off = 32; off > 0; off >>= 1) mx = fmaxf(mx, __shfl_xor(mx, off, 64));
        float e = expf(acc - mx);
        float ssum = e;
        for (int off = 32; off > 0; off >>= 1) ssum += __shfl_xor(ssum, off, 64);
        softm[b * C_DIM + t] = e / ssum;
    }
}

// one-shot: fea_bank (with f_norm substitution) -> pre-permuted bf16 32-cand chunks.
__global__ __launch_bounds__(256) void k_convert(const float* __restrict__ fea_bank,
                                                 const float* __restrict__ f_norm,
                                                 const int* __restrict__ pos_of,
                                                 short* __restrict__ bank) {
    int cc = blockIdx.x, t = threadIdx.x;
    int r = t >> 2, q4 = t & 3;
    int n = cc * 64 + r;
    int p = pos_of[n];
    const float* src = (p >= 0) ? (f_norm + (size_t)p * D_DIM)
                                : (fea_bank + (size_t)n * D_DIM);
    short* dst = bank + (size_t)(cc * 2 + (r >> 5)) * CH32_SH;
    int rl = r & 31;
    #pragma unroll
    for (int i = 0; i < 8; ++i) {
        int kk = i * 32 + q4 * 8;
        float4 a = *(const float4*)(src + kk);
        float4 b = *(const float4*)(src + kk + 4);
        int e = ((kk >> 4) * 64) + (((kk >> 3) & 1) * 32) + rl;
        *(u16x8*)(dst + (size_t)e * 8) = pack8(a, b);
    }
}

// permute query rows into fragment-order tiles AND plain bf16 rows
__global__ __launch_bounds__(256) void k_permq(const float* __restrict__ rows,
                                               const float* __restrict__ fea_bank,
                                               const int* __restrict__ idx,
                                               const int* __restrict__ pos_of,
                                               short* __restrict__ dst,
                                               unsigned short* __restrict__ qplain) {
    int tile = blockIdx.x, t = threadIdx.x;
    int r = t >> 2, q4 = t & 3;
    const float* src;
    if (idx) {
        int n = idx[tile * 64 + r];
        int p = pos_of[n];
        src = (p >= 0) ? (rows + (size_t)p * D_DIM) : (fea_bank + (size_t)n * D_DIM);
    } else {
        src = rows + (size_t)(tile * 64 + r) * D_DIM;
    }
    short* d = dst + (size_t)tile * QTILE_SH;
    unsigned short* qp = qplain + (size_t)(tile * 64 + r) * D_DIM;
    #pragma unroll
    for (int i = 0; i < 8; ++i) {
        int kk = i * 32 + q4 * 8;
        float4 a = *(const float4*)(src + kk);
        float4 b = *(const float4*)(src + kk + 4);
        u16x8 h = pack8(a, b);
        int e = ((kk >> 4) * 128) + ((r >> 5) * 64) + (((kk >> 3) & 1) * 32) + (r & 31);
        *(u16x8*)(d + (size_t)e * 8) = h;
        *(u16x8*)(qp + kk) = h;
    }
}

// PHASE 1: MFMA distance + per-(query,chunk) MAX.
// 4 waves x 64 queries = 256 queries/block; 2 acc chains per wave.
// amdgpu_waves_per_eu(2,2): pin occupancy target to exactly 2 waves/EU so the
// register allocator has (and uses) a 256-VGPR budget -> B-frags stay TRULY
// resident (no per-chunk L2 refetch, the measured ~4.6k cyc/chunk wall).
// 3-DEEP pipeline: 4 LDS buffers, counted vmcnt. LDS = 64KB + 16KB = 80KB.
__global__ __launch_bounds__(256, 2)
__attribute__((amdgpu_waves_per_eu(2, 2)))
void dist_max(const short* __restrict__ qbf,
              const short* __restrict__ bank,
              unsigned short* __restrict__ cmax,
              int nqt, int swz,
              int S, int nchj) {
    __shared__ __align__(16) short sbuf[4 * CH32_SH];        // 64 KB quad buffer
    __shared__ unsigned short cmaxbuf[32 * 256];             // 16 KB [ch][q]

    int slab, qt;
    if (swz) {
        int bid = blockIdx.x;
        int xcd = bid & 7;
        int rem = bid >> 3;
        qt = rem % nqt;
        slab = (rem / nqt) * 8 + xcd;
        if (slab >= S) return;
    } else {
        slab = blockIdx.x;
        qt = blockIdx.y;
    }
    const int cfirst = slab * nchj;
    int nch = NCH32 - cfirst; if (nch > nchj) nch = nchj;    // nch >= 10 always

    const int t   = threadIdx.x;
    const int w   = t >> 6;
    const int l   = t & 63;
    const int khv = l >> 5;
    const int col = l & 31;

    // ---- B-frags: this wave's 64 queries (one full 64-row tile), resident ----
    const short* qtile = qbf + (size_t)(qt * 4 + w) * QTILE_SH;
    bf16x8 bfr0[16], bfr1[16];
    #pragma unroll
    for (int ks = 0; ks < 16; ++ks) {
        bfr0[ks] = *(const bf16x8*)(qtile + (size_t)(ks * 128      + l) * 8);
        bfr1[ks] = *(const bf16x8*)(qtile + (size_t)(ks * 128 + 64 + l) * 8);
    }

    const short* sbase = bank + (size_t)cfirst * CH32_SH;

    // ---- prologue: issue loads for chunks 0,1,2 (12 loads in flight) ----
    #pragma unroll
    for (int c = 0; c < 3; ++c) {
        const short* g = sbase + (size_t)c * CH32_SH;
        short* lbase = sbuf + (size_t)c * CH32_SH;
        #pragma unroll
        for (int i = 0; i < 4; ++i) {
            const short* gp = g + (size_t)(i * 256 + t) * 8;
            short* lp = lbase + (size_t)(i * 256 + w * 64) * 8;
            __builtin_amdgcn_global_load_lds(
                (const __attribute__((address_space(1))) void*)gp,
                (__attribute__((address_space(3))) void*)lp, 16, 0, 0);
        }
    }

    for (int ch = 0; ch < nch; ++ch) {
        int ahead = nch - 1 - ch;
        if (ahead >= 2)      asm volatile("s_waitcnt vmcnt(8)" ::: "memory");
        else if (ahead == 1) asm volatile("s_waitcnt vmcnt(4)" ::: "memory");
        else                 asm volatile("s_waitcnt vmcnt(0)" ::: "memory");
        __builtin_amdgcn_s_barrier();
        __builtin_amdgcn_sched_barrier(0);

        const short* cb = sbuf + (size_t)(ch & 3) * CH32_SH;

        f32x16 a0 = {}, a1 = {};
        __builtin_amdgcn_s_setprio(1);
        #pragma unroll
        for (int ks = 0; ks < 16; ++ks) {
            bf16x8 fa = *(const bf16x8*)(cb + (size_t)(ks * 64 + l) * 8);
            a0 = __builtin_amdgcn_mfma_f32_32x32x16_bf16(fa, bfr0[ks], a0, 0, 0, 0);
            a1 = __builtin_amdgcn_mfma_f32_32x32x16_bf16(fa, bfr1[ks], a1, 0, 0, 0);
        }
        __builtin_amdgcn_s_setprio(0);

        float m0 = a0[0], m1 = a1[0];
        #pragma unroll
        for (int r = 1; r < 16; ++r) { m0 = fmaxf(m0, a0[r]); m1 = fmaxf(m1, a1[r]); }
        m0 = fmaxf(m0, __shfl_xor(m0, 32, 64));
        m1 = fmaxf(m1, __shfl_xor(m1, 32, 64));
        if (khv == 0) {
            cmaxbuf[ch * 256 + w * 64 + col]      = bf16rne(m0);
            cmaxbuf[ch * 256 + w * 64 + 32 + col] = bf16rne(m1);
        }

        if (ch + 3 < nch) {
            const short* g = sbase + (size_t)(ch + 3) * CH32_SH;
            short* lbase = sbuf + (size_t)((ch + 3) & 3) * CH32_SH;
            #pragma unroll
            for (int i = 0; i < 4; ++i) {
                const short* gp = g + (size_t)(i * 256 + t) * 8;
                short* lp = lbase + (size_t)(i * 256 + w * 64) * 8;
                __builtin_amdgcn_global_load_lds(
                    (const __attribute__((address_space(1))) void*)gp,
                    (__attribute__((address_space(3))) void*)lp, 16, 0, 0);
            }
        }
    }

    // ---- coalesced write-out: thread t owns query row t (256 queries) ----
    __syncthreads();
    {
        size_t gbase = (size_t)(qt * 256 + t) * CMSTR + cfirst;
        int c0 = 0;
        for (; c0 + 8 <= nch; c0 += 8) {
            u16x8 h;
            #pragma unroll
            for (int i = 0; i < 8; ++i) h[i] = cmaxbuf[(c0 + i) * 256 + t];
            *(u16x8*)(cmax + gbase + c0) = h;
        }
        for (; c0 < nch; ++c0) cmax[gbase + c0] = cmaxbuf[c0 * 256 + t];
        // pad the row tail (last job only) with -FLT_MAX so vector scans are exact
        int cend = CMSTR - cfirst; if (cend > nchj) cend = nchj;
        for (int cp = nch; cp < cend; ++cp) cmax[gbase + cp] = 0xFF7F;
    }
}

// PHASE 2: per query: tau = 6th-best chunk-max; rescore chunks >= tau - 6e-3
// from the bf16 bank; exact top-6 -> write ranks 1..5.
__global__ __launch_bounds__(256) void k_select(const unsigned short* __restrict__ cmax,
                                                const unsigned short* __restrict__ qplain,
                                                const short* __restrict__ bank,
                                                int* __restrict__ out_idx) {
    int q = blockIdx.x, t = threadIdx.x;
    __shared__ float sv[256][6];
    __shared__ int   si[256][6];
    __shared__ float qrow[256];
    __shared__ int cnt;
    __shared__ int list[MAXC];

    const unsigned short* row = cmax + (size_t)q * CMSTR;

    float lv[6]; int li[6];
    #pragma unroll
    for (int k = 0; k < 6; ++k) { lv[k] = -3.4e38f; li[k] = 0x7fffffff; }
    for (int c0 = t * 8; c0 < CMSTR; c0 += 2048) {
        u16x8 h = *(const u16x8*)(row + c0);
        float m8 = bf16f(h[0]);
        #pragma unroll
        for (int i = 1; i < 8; ++i) m8 = fmaxf(m8, bf16f(h[i]));
        if (better(m8, c0, lv[5], li[5])) {
            #pragma unroll
            for (int i = 0; i < 8; ++i) {
                int c = c0 + i;
                if (c < NCH32) insert6f(lv, li, bf16f(h[i]), c);
            }
        }
    }
    #pragma unroll
    for (int k = 0; k < 6; ++k) { sv[t][k] = lv[k]; si[t][k] = li[k]; }
    if (t == 0) cnt = 0;
    __syncthreads();
    for (int w = 128; w >= 1; w >>= 1) {
        if (t < w) {
            float ov[6]; int oi[6];
            merge6(sv[t], si[t], sv[t + w], si[t + w], ov, oi);
            #pragma unroll
            for (int k = 0; k < 6; ++k) { sv[t][k] = ov[k]; si[t][k] = oi[k]; }
        }
        __syncthreads();
    }
    float tauM = sv[0][5] - 6e-3f;
    __syncthreads();

    for (int c0 = t * 8; c0 < CMSTR; c0 += 2048) {
        u16x8 h = *(const u16x8*)(row + c0);
        float m8 = bf16f(h[0]);
        #pragma unroll
        for (int i = 1; i < 8; ++i) m8 = fmaxf(m8, bf16f(h[i]));
        if (m8 >= tauM) {
            #pragma unroll
            for (int i = 0; i < 8; ++i) {
                int c = c0 + i;
                if (c < NCH32 && bf16f(h[i]) >= tauM) {
                    int k = atomicAdd(&cnt, 1);
                    if (k < MAXC) list[k] = c;
                }
            }
        }
    }
    qrow[t] = bf16f(qplain[(size_t)q * D_DIM + t]);
    __syncthreads();
    int nc = cnt < MAXC ? cnt : MAXC;

    float bv[6]; int bi[6];
    #pragma unroll
    for (int k = 0; k < 6; ++k) { bv[k] = -3.4e38f; bi[k] = 0x7fffffff; }
    const int cand = t >> 3, j = t & 7;
    for (int ci = 0; ci < nc; ++ci) {
        int c = list[ci];
        const short* cb = bank + (size_t)c * CH32_SH;
        u16x8 h0 = *(const u16x8*)(cb + (size_t)(128 * j +  0 + cand) * 8);
        u16x8 h1 = *(const u16x8*)(cb + (size_t)(128 * j + 32 + cand) * 8);
        u16x8 h2 = *(const u16x8*)(cb + (size_t)(128 * j + 64 + cand) * 8);
        u16x8 h3 = *(const u16x8*)(cb + (size_t)(128 * j + 96 + cand) * 8);
        int d0 = j * 32;
        float acc = 0.f;
        #pragma unroll
        for (int d = 0; d < 8; ++d) {
            acc = fmaf(bf16f(h0[d]), qrow[d0 + d], acc);
            acc = fmaf(bf16f(h1[d]), qrow[d0 + 8 + d], acc);
            acc = fmaf(bf16f(h2[d]), qrow[d0 + 16 + d], acc);
            acc = fmaf(bf16f(h3[d]), qrow[d0 + 24 + d], acc);
        }
        acc += __shfl_down(acc, 4, 8);
        acc += __shfl_down(acc, 2, 8);
        acc += __shfl_down(acc, 1, 8);
        if (j == 0) insert6f(bv, bi, acc, c * CH32 + cand);
    }

    #pragma unroll
    for (int k = 0; k < 6; ++k) { sv[t][k] = bv[k]; si[t][k] = bi[k]; }
    __syncthreads();
    for (int w = 128; w >= 1; w >>= 1) {
        if (t < w) {
            float ov[6]; int oi[6];
            merge6(sv[t], si[t], sv[t + w], si[t + w], ov, oi);
            #pragma unroll
            for (int k = 0; k < 6; ++k) { sv[t][k] = ov[k]; si[t][k] = oi[k]; }
        }
        __syncthreads();
    }
    if (t == 0) {
        for (int k = 1; k < 6; ++k) out_idx[q * K_TOP + k - 1] = si[0][k];
    }
}

__global__ void k_loss(const float* __restrict__ softm, const float* __restrict__ score_bank,
                       const int* __restrict__ pos_of, const int* __restrict__ idx_near,
                       const int* __restrict__ idx_nn, const int* __restrict__ trg,
                       float* accp) {
    int b = blockIdx.x, c = threadIdx.x;   // 64 threads
    float p_bc = softm[b * C_DIM + c];
    float part = 0.f;
    for (int k = 0; k < K_TOP; ++k) {
        for (int j = 0; j < K_TOP; ++j) {
            int n = idx_nn[(b * K_TOP + k) * K_TOP + j];
            int p = pos_of[n];
            const float* srow = (p >= 0) ? (softm + (size_t)p * C_DIM)
                                         : (score_bank + (size_t)n * C_DIM);
            float s = srow[c];
            float v = s * (logf(s) - p_bc);
            for (int off = 32; off > 0; off >>= 1) v += __shfl_down(v, off, 64);
            if (c == 0) part += 0.1f * v;
        }
    }
    for (int k = 0; k < K_TOP; ++k) {
        int n = idx_near[b * K_TOP + k];
        int p = pos_of[n];
        const float* srow = (p >= 0) ? (softm + (size_t)p * C_DIM)
                                     : (score_bank + (size_t)n * C_DIM);
        float s = srow[c];
        float v = s * (logf(s) - p_bc);
        for (int off = 32; off > 0; off >>= 1) v += __shfl_down(v, off, 64);
        if (c == 0) {
            int m = 0;
            for (int j = 0; j < K_TOP; ++j)
                m += (idx_nn[(b * K_TOP + k) * K_TOP + j] == trg[b]) ? 1 : 0;
            float w = (m > 0) ? (float)m : 0.1f;
            part += w * v;
        }
    }
    if (c == 0) atomicAdd(accp, part * (1.0f / (float)B_SZ));
}

__global__ void k_final(const float* __restrict__ softm, const float* __restrict__ accp,
                        float* __restrict__ out) {
    int c = threadIdx.x;   // 64
    float m = 0.f;
    for (int b = 0; b < B_SZ; ++b) m += softm[b * C_DIM + c];
    m *= (1.0f / (float)B_SZ);
    float g = m * logf(m + 1e-5f);
    for (int off = 32; off > 0; off >>= 1) g += __shfl_down(g, off, 64);
    if (c == 0) out[0] = accp[0] + g;
}

extern "C" void kernel_launch(void* const* d_in, const int* in_sizes, int n_in,
                              void* d_out, int out_size, void* d_ws, size_t ws_size,
                              hipStream_t stream) {
    const float* features   = (const float*)d_in[0];
    const float* W          = (const float*)d_in[1];
    const float* bias       = (const float*)d_in[2];
    const float* fea_bank   = (const float*)d_in[3];
    const float* score_bank = (const float*)d_in[4];
    const int*   trg        = (const int*)d_in[5];
    float* out = (float*)d_out;

    char* ws = (char*)d_ws;
    size_t off = 0;
    auto alloc = [&](size_t bytes) -> void* {
        void* p = ws + off;
        off = (off + bytes + 255) & ~(size_t)255;
        return p;
    };
    short* bankbf   = (short*)alloc((size_t)NCH32 * CH32_SH * 2);            // 102.4 MB
    short* q1bf     = (short*)alloc((size_t)(B_SZ / 64) * QTILE_SH * 2);
    short* q2bf     = (short*)alloc((size_t)(B_SZ * K_TOP / 64) * QTILE_SH * 2);
    unsigned short* qplain1 = (unsigned short*)alloc((size_t)B_SZ * D_DIM * 2);
    unsigned short* qplain2 = (unsigned short*)alloc((size_t)B_SZ * K_TOP * D_DIM * 2);
    float* f_norm   = (float*)alloc((size_t)B_SZ * D_DIM * 4);
    float* softm    = (float*)alloc((size_t)B_SZ * C_DIM * 4);
    int*   pos_of   = (int*)alloc((size_t)N_CAND * 4);
    float* accp     = (float*)alloc(4);
    int*   idx_near = (int*)alloc((size_t)B_SZ * K_TOP * 4);
    int*   idx_nn   = (int*)alloc((size_t)B_SZ * K_TOP * K_TOP * 4);
    unsigned short* cmax1 = (unsigned short*)alloc((size_t)B_SZ * CMSTR * 2);
    unsigned short* cmax2 = (unsigned short*)alloc((size_t)B_SZ * K_TOP * CMSTR * 2);

    k_init<<<dim3((N_CAND + 255) / 256), dim3(256), 0, stream>>>(pos_of, accp);
    k_scatter<<<dim3(1), dim3(256), 0, stream>>>(trg, pos_of);
    k_prep<<<dim3(B_SZ), dim3(256), 0, stream>>>(features, W, bias, f_norm, softm);

    k_convert<<<dim3(NCH32 / 2), dim3(256), 0, stream>>>(fea_bank, f_norm, pos_of, bankbf);
    k_permq<<<dim3(B_SZ / 64), dim3(256), 0, stream>>>(
        f_norm, fea_bank, nullptr, pos_of, q1bf, qplain1);

    // pass 1 phase 1: 256 queries = 1 block-qtile of 256; 16-chunk jobs
    dist_max<<<dim3(S1, 1), dim3(256), 0, stream>>>(
        q1bf, bankbf, cmax1, 1, 0, S1, NCHJ1);
    k_select<<<dim3(B_SZ), dim3(256), 0, stream>>>(cmax1, qplain1, bankbf, idx_near);

    k_permq<<<dim3(B_SZ * K_TOP / 64), dim3(256), 0, stream>>>(
        f_norm, fea_bank, idx_near, pos_of, q2bf, qplain2);

    // pass 2 phase 1: 1280 queries = 5 block-qtiles of 256; 32-chunk jobs, XCD-grouped
    {
        int nqt = (B_SZ * K_TOP) / 256;           // 5
        int nsg = (S2 + 7) / 8;                   // 25
        dist_max<<<dim3(nsg * 8 * nqt), dim3(256), 0, stream>>>(
            q2bf, bankbf, cmax2, nqt, 1, S2, NCHJ2);
    }
    k_select<<<dim3(B_SZ * K_TOP), dim3(256), 0, stream>>>(cmax2, qplain2, bankbf, idx_nn);

    k_loss<<<dim3(B_SZ), dim3(64), 0, stream>>>(softm, score_bank, pos_of, idx_near, idx_nn, trg, accp);
    k_final<<<dim3(1), dim3(64), 0, stream>>>(softm, accp, out);
}

// Round 20
// 299.697 us; speedup vs baseline: 1.4780x; 1.0574x over previous
//
#include <hip/hip_runtime.h>
#include <hip/hip_bf16.h>
#include <math.h>

#define B_SZ   256
#define D_DIM  256
#define C_DIM  64
#define N_CAND 200000
#define K_TOP  5
#define CH32   32
#define CH32_SH 8192                          // shorts per 32-cand chunk (16KB)
#define QTILE_SH 16384                        // shorts per 64-query tile (32KB)
#define NCH32  (N_CAND / CH32)                // 6250 chunks (exact)
#define CMSTR  6256                           // cmax row stride (16B-aligned, padded)
#define NCHJ2  32                             // chunks/job pass 2
#define S2     ((NCH32 + NCHJ2 - 1) / NCHJ2)  // 196 (last job 10 chunks)
#define MAXC   192                            // max rescored chunks per query

typedef short bf16x8 __attribute__((ext_vector_type(8)));
typedef float f32x16 __attribute__((ext_vector_type(16)));
typedef unsigned short u16x8 __attribute__((ext_vector_type(8)));

__device__ __forceinline__ bool better(float v1, int i1, float v2, int i2) {
    return (v1 > v2) || (v1 == v2 && i1 < i2);
}

__device__ __forceinline__ void insert6f(float* lv, int* li, float v, int idx) {
    if (better(v, idx, lv[5], li[5])) {
        lv[5] = v; li[5] = idx;
        #pragma unroll
        for (int k = 5; k > 0; --k) {
            if (better(lv[k], li[k], lv[k - 1], li[k - 1])) {
                float tv = lv[k]; lv[k] = lv[k - 1]; lv[k - 1] = tv;
                int   ti = li[k]; li[k] = li[k - 1]; li[k - 1] = ti;
            }
        }
    }
}

__device__ __forceinline__ void merge6(const float* av, const int* ai,
                                       const float* bv, const int* bi,
                                       float* ov, int* oi) {
    int ia = 0, ib = 0;
    #pragma unroll
    for (int k = 0; k < 6; ++k) {
        bool ta;
        if (ia >= 6)      ta = false;
        else if (ib >= 6) ta = true;
        else              ta = better(av[ia], ai[ia], bv[ib], bi[ib]);
        if (ta) { ov[k] = av[ia]; oi[k] = ai[ia]; ++ia; }
        else    { ov[k] = bv[ib]; oi[k] = bi[ib]; ++ib; }
    }
}

__device__ __forceinline__ unsigned short bf16rne(float x) {
    unsigned int u = __float_as_uint(x);
    unsigned int r = u + 0x7fffu + ((u >> 16) & 1u);
    return (unsigned short)(r >> 16);
}

__device__ __forceinline__ float bf16f(unsigned short h) {
    return __uint_as_float(((unsigned)h) << 16);
}

__device__ __forceinline__ u16x8 pack8(float4 a, float4 b) {
    u16x8 h;
    h[0] = bf16rne(a.x); h[1] = bf16rne(a.y); h[2] = bf16rne(a.z); h[3] = bf16rne(a.w);
    h[4] = bf16rne(b.x); h[5] = bf16rne(b.y); h[6] = bf16rne(b.z); h[7] = bf16rne(b.w);
    return h;
}

__global__ void k_init(int* pos_of, float* accp) {
    int i = blockIdx.x * 256 + threadIdx.x;
    if (i < N_CAND) pos_of[i] = -1;
    if (i == 0) accp[0] = 0.f;
}

__global__ void k_scatter(const int* __restrict__ trg, int* __restrict__ pos_of) {
    int j = threadIdx.x;
    atomicMax(&pos_of[trg[j]], j);
}

__global__ __launch_bounds__(256) void k_prep(const float* __restrict__ features,
                                              const float* __restrict__ W,
                                              const float* __restrict__ bias,
                                              float* __restrict__ f_norm,
                                              float* __restrict__ softm) {
    int b = blockIdx.x, t = threadIdx.x;
    __shared__ float row[256];
    __shared__ float red[256];
    float x = features[b * D_DIM + t];
    row[t] = x; red[t] = x * x;
    __syncthreads();
    for (int s = 128; s > 0; s >>= 1) {
        if (t < s) red[t] += red[t + s];
        __syncthreads();
    }
    float nrm = fmaxf(sqrtf(red[0]), 1e-12f);
    f_norm[b * D_DIM + t] = x / nrm;
    if (t < C_DIM) {
        float acc = bias[t];
        for (int d = 0; d < D_DIM; ++d) acc = fmaf(row[d], W[d * C_DIM + t], acc);
        float mx = acc;
        for (int off = 32; off > 0; off >>= 1) mx = fmaxf(mx, __shfl_xor(mx, off, 64));
        float e = expf(acc - mx);
        float ssum = e;
        for (int off = 32; off > 0; off >>= 1) ssum += __shfl_xor(ssum, off, 64);
        softm[b * C_DIM + t] = e / ssum;
    }
}

// permute query rows into fragment-order tiles AND plain bf16 rows; also pad
// the cmax row tails (cols 6250..6255) so k_select's vector scans are exact.
__global__ __launch_bounds__(256) void k_permq(const float* __restrict__ rows,
                                               const float* __restrict__ fea_bank,
                                               const int* __restrict__ idx,
                                               const int* __restrict__ pos_of,
                                               short* __restrict__ dst,
                                               unsigned short* __restrict__ qplain,
                                               unsigned short* __restrict__ cmax_pad) {
    int tile = blockIdx.x, t = threadIdx.x;
    int r = t >> 2, q4 = t & 3;
    const float* src;
    if (idx) {
        int n = idx[tile * 64 + r];
        int p = pos_of[n];
        src = (p >= 0) ? (rows + (size_t)p * D_DIM) : (fea_bank + (size_t)n * D_DIM);
    } else {
        src = rows + (size_t)(tile * 64 + r) * D_DIM;
    }
    short* d = dst + (size_t)tile * QTILE_SH;
    unsigned short* qp = qplain + (size_t)(tile * 64 + r) * D_DIM;
    #pragma unroll
    for (int i = 0; i < 8; ++i) {
        int kk = i * 32 + q4 * 8;
        float4 a = *(const float4*)(src + kk);
        float4 b = *(const float4*)(src + kk + 4);
        u16x8 h = pack8(a, b);
        int e = ((kk >> 4) * 128) + ((r >> 5) * 64) + (((kk >> 3) & 1) * 32) + (r & 31);
        *(u16x8*)(d + (size_t)e * 8) = h;
        *(u16x8*)(qp + kk) = h;
    }
    if (t < 64) {
        size_t base = (size_t)(tile * 64 + t) * CMSTR + NCH32;
        #pragma unroll
        for (int k = 0; k < 6; ++k) cmax_pad[base + k] = 0xFF7F;
    }
}

// FUSED: bank convert (fea_bank + f_norm substitution -> pre-permuted bf16)
// + pass-1 distance max vs the 256 batch queries.
// Block cc: rows 64cc..64cc+63 = chunks (2cc, 2cc+1). Converted data staged in
// LDS (fragment order) -> 2x(16x2) MFMA per wave -> cmax1 cols 2cc,2cc+1.
__global__ __launch_bounds__(256) void k_convert(const float* __restrict__ fea_bank,
                                                 const float* __restrict__ f_norm,
                                                 const int* __restrict__ pos_of,
                                                 const short* __restrict__ qbf,
                                                 short* __restrict__ bank,
                                                 unsigned short* __restrict__ cmax) {
    __shared__ __align__(16) short ls[2 * CH32_SH];          // 32 KB staged chunks
    __shared__ unsigned short cmaxbuf[2 * 256];              // 1 KB

    int cc = blockIdx.x, t = threadIdx.x;
    int r = t >> 2, q4 = t & 3;
    int n = cc * 64 + r;
    int p = pos_of[n];
    const float* src = (p >= 0) ? (f_norm + (size_t)p * D_DIM)
                                : (fea_bank + (size_t)n * D_DIM);
    short* dst = bank + (size_t)(cc * 2 + (r >> 5)) * CH32_SH;
    short* lds = ls + (size_t)(r >> 5) * CH32_SH;
    int rl = r & 31;
    #pragma unroll
    for (int i = 0; i < 8; ++i) {
        int kk = i * 32 + q4 * 8;
        float4 a = *(const float4*)(src + kk);
        float4 b = *(const float4*)(src + kk + 4);
        u16x8 h = pack8(a, b);
        int e = ((kk >> 4) * 64) + (((kk >> 3) & 1) * 32) + rl;
        *(u16x8*)(dst + (size_t)e * 8) = h;
        *(u16x8*)(lds + (size_t)e * 8) = h;
    }

    // ---- B-frags: wave w's 64 queries of the 256 batch queries ----
    const int w   = t >> 6;
    const int l   = t & 63;
    const int khv = l >> 5;
    const int col = l & 31;
    const short* qtile = qbf + (size_t)w * QTILE_SH;
    bf16x8 bfr0[16], bfr1[16];
    #pragma unroll
    for (int ks = 0; ks < 16; ++ks) {
        bfr0[ks] = *(const bf16x8*)(qtile + (size_t)(ks * 128      + l) * 8);
        bfr1[ks] = *(const bf16x8*)(qtile + (size_t)(ks * 128 + 64 + l) * 8);
    }
    __syncthreads();

    #pragma unroll
    for (int ch = 0; ch < 2; ++ch) {
        const short* cb = ls + (size_t)ch * CH32_SH;
        f32x16 a0 = {}, a1 = {};
        #pragma unroll
        for (int ks = 0; ks < 16; ++ks) {
            bf16x8 fa = *(const bf16x8*)(cb + (size_t)(ks * 64 + l) * 8);
            a0 = __builtin_amdgcn_mfma_f32_32x32x16_bf16(fa, bfr0[ks], a0, 0, 0, 0);
            a1 = __builtin_amdgcn_mfma_f32_32x32x16_bf16(fa, bfr1[ks], a1, 0, 0, 0);
        }
        float m0 = a0[0], m1 = a1[0];
        #pragma unroll
        for (int rr = 1; rr < 16; ++rr) { m0 = fmaxf(m0, a0[rr]); m1 = fmaxf(m1, a1[rr]); }
        m0 = fmaxf(m0, __shfl_xor(m0, 32, 64));
        m1 = fmaxf(m1, __shfl_xor(m1, 32, 64));
        if (khv == 0) {
            cmaxbuf[ch * 256 + w * 64 + col]      = bf16rne(m0);
            cmaxbuf[ch * 256 + w * 64 + 32 + col] = bf16rne(m1);
        }
    }
    __syncthreads();
    {
        // one aligned 4B store per query: cols (2cc, 2cc+1) of row t
        unsigned v = (unsigned)cmaxbuf[t] | ((unsigned)cmaxbuf[256 + t] << 16);
        *(unsigned*)&cmax[(size_t)t * CMSTR + cc * 2] = v;
    }
}

// PHASE 1 (pass 2 only): MFMA distance + per-(query,chunk) MAX.
// 4 waves x 64 queries = 256 queries/block; 3-deep pipeline, counted vmcnt.
__global__ __launch_bounds__(256, 2)
__attribute__((amdgpu_waves_per_eu(2, 2)))
void dist_max(const short* __restrict__ qbf,
              const short* __restrict__ bank,
              unsigned short* __restrict__ cmax,
              int nqt, int S, int nchj) {
    __shared__ __align__(16) short sbuf[4 * CH32_SH];        // 64 KB quad buffer
    __shared__ unsigned short cmaxbuf[32 * 256];             // 16 KB [ch][q]

    int bid = blockIdx.x;
    int xcd = bid & 7;
    int rem = bid >> 3;
    int qt = rem % nqt;
    int slab = (rem / nqt) * 8 + xcd;
    if (slab >= S) return;

    const int cfirst = slab * nchj;
    int nch = NCH32 - cfirst; if (nch > nchj) nch = nchj;

    const int t   = threadIdx.x;
    const int w   = t >> 6;
    const int l   = t & 63;
    const int khv = l >> 5;
    const int col = l & 31;

    const short* qtile = qbf + (size_t)(qt * 4 + w) * QTILE_SH;
    bf16x8 bfr0[16], bfr1[16];
    #pragma unroll
    for (int ks = 0; ks < 16; ++ks) {
        bfr0[ks] = *(const bf16x8*)(qtile + (size_t)(ks * 128      + l) * 8);
        bfr1[ks] = *(const bf16x8*)(qtile + (size_t)(ks * 128 + 64 + l) * 8);
    }

    const short* sbase = bank + (size_t)cfirst * CH32_SH;

    #pragma unroll
    for (int c = 0; c < 3; ++c) {
        const short* g = sbase + (size_t)c * CH32_SH;
        short* lbase = sbuf + (size_t)c * CH32_SH;
        #pragma unroll
        for (int i = 0; i < 4; ++i) {
            const short* gp = g + (size_t)(i * 256 + t) * 8;
            short* lp = lbase + (size_t)(i * 256 + w * 64) * 8;
            __builtin_amdgcn_global_load_lds(
                (const __attribute__((address_space(1))) void*)gp,
                (__attribute__((address_space(3))) void*)lp, 16, 0, 0);
        }
    }

    for (int ch = 0; ch < nch; ++ch) {
        int ahead = nch - 1 - ch;
        if (ahead >= 2)      asm volatile("s_waitcnt vmcnt(8)" ::: "memory");
        else if (ahead == 1) asm volatile("s_waitcnt vmcnt(4)" ::: "memory");
        else                 asm volatile("s_waitcnt vmcnt(0)" ::: "memory");
        __builtin_amdgcn_s_barrier();
        __builtin_amdgcn_sched_barrier(0);

        const short* cb = sbuf + (size_t)(ch & 3) * CH32_SH;

        f32x16 a0 = {}, a1 = {};
        __builtin_amdgcn_s_setprio(1);
        #pragma unroll
        for (int ks = 0; ks < 16; ++ks) {
            bf16x8 fa = *(const bf16x8*)(cb + (size_t)(ks * 64 + l) * 8);
            a0 = __builtin_amdgcn_mfma_f32_32x32x16_bf16(fa, bfr0[ks], a0, 0, 0, 0);
            a1 = __builtin_amdgcn_mfma_f32_32x32x16_bf16(fa, bfr1[ks], a1, 0, 0, 0);
        }
        __builtin_amdgcn_s_setprio(0);

        float m0 = a0[0], m1 = a1[0];
        #pragma unroll
        for (int r = 1; r < 16; ++r) { m0 = fmaxf(m0, a0[r]); m1 = fmaxf(m1, a1[r]); }
        m0 = fmaxf(m0, __shfl_xor(m0, 32, 64));
        m1 = fmaxf(m1, __shfl_xor(m1, 32, 64));
        if (khv == 0) {
            cmaxbuf[ch * 256 + w * 64 + col]      = bf16rne(m0);
            cmaxbuf[ch * 256 + w * 64 + 32 + col] = bf16rne(m1);
        }

        if (ch + 3 < nch) {
            const short* g = sbase + (size_t)(ch + 3) * CH32_SH;
            short* lbase = sbuf + (size_t)((ch + 3) & 3) * CH32_SH;
            #pragma unroll
            for (int i = 0; i < 4; ++i) {
                const short* gp = g + (size_t)(i * 256 + t) * 8;
                short* lp = lbase + (size_t)(i * 256 + w * 64) * 8;
                __builtin_amdgcn_global_load_lds(
                    (const __attribute__((address_space(1))) void*)gp,
                    (__attribute__((address_space(3))) void*)lp, 16, 0, 0);
            }
        }
    }

    __syncthreads();
    {
        size_t gbase = (size_t)(qt * 256 + t) * CMSTR + cfirst;
        int c0 = 0;
        for (; c0 + 8 <= nch; c0 += 8) {
            u16x8 h;
            #pragma unroll
            for (int i = 0; i < 8; ++i) h[i] = cmaxbuf[(c0 + i) * 256 + t];
            *(u16x8*)(cmax + gbase + c0) = h;
        }
        for (; c0 < nch; ++c0) cmax[gbase + c0] = cmaxbuf[c0 * 256 + t];
    }
}

// PHASE 2: per query: tau = 6th-best chunk-max; rescore chunks >= tau - 6e-3
// from the bf16 bank; exact top-6 -> write ranks 1..5.
__global__ __launch_bounds__(256) void k_select(const unsigned short* __restrict__ cmax,
                                                const unsigned short* __restrict__ qplain,
                                                const short* __restrict__ bank,
                                                int* __restrict__ out_idx) {
    int q = blockIdx.x, t = threadIdx.x;
    __shared__ float sv[256][6];
    __shared__ int   si[256][6];
    __shared__ float qrow[256];
    __shared__ int cnt;
    __shared__ int list[MAXC];

    const unsigned short* row = cmax + (size_t)q * CMSTR;

    float lv[6]; int li[6];
    #pragma unroll
    for (int k = 0; k < 6; ++k) { lv[k] = -3.4e38f; li[k] = 0x7fffffff; }
    for (int c0 = t * 8; c0 < CMSTR; c0 += 2048) {
        u16x8 h = *(const u16x8*)(row + c0);
        float m8 = bf16f(h[0]);
        #pragma unroll
        for (int i = 1; i < 8; ++i) m8 = fmaxf(m8, bf16f(h[i]));
        if (better(m8, c0, lv[5], li[5])) {
            #pragma unroll
            for (int i = 0; i < 8; ++i) {
                int c = c0 + i;
                if (c < NCH32) insert6f(lv, li, bf16f(h[i]), c);
            }
        }
    }
    #pragma unroll
    for (int k = 0; k < 6; ++k) { sv[t][k] = lv[k]; si[t][k] = li[k]; }
    if (t == 0) cnt = 0;
    __syncthreads();
    for (int w = 128; w >= 1; w >>= 1) {
        if (t < w) {
            float ov[6]; int oi[6];
            merge6(sv[t], si[t], sv[t + w], si[t + w], ov, oi);
            #pragma unroll
            for (int k = 0; k < 6; ++k) { sv[t][k] = ov[k]; si[t][k] = oi[k]; }
        }
        __syncthreads();
    }
    float tauM = sv[0][5] - 6e-3f;
    __syncthreads();

    for (int c0 = t * 8; c0 < CMSTR; c0 += 2048) {
        u16x8 h = *(const u16x8*)(row + c0);
        float m8 = bf16f(h[0]);
        #pragma unroll
        for (int i = 1; i < 8; ++i) m8 = fmaxf(m8, bf16f(h[i]));
        if (m8 >= tauM) {
            #pragma unroll
            for (int i = 0; i < 8; ++i) {
                int c = c0 + i;
                if (c < NCH32 && bf16f(h[i]) >= tauM) {
                    int k = atomicAdd(&cnt, 1);
                    if (k < MAXC) list[k] = c;
                }
            }
        }
    }
    qrow[t] = bf16f(qplain[(size_t)q * D_DIM + t]);
    __syncthreads();
    int nc = cnt < MAXC ? cnt : MAXC;

    float bv[6]; int bi[6];
    #pragma unroll
    for (int k = 0; k < 6; ++k) { bv[k] = -3.4e38f; bi[k] = 0x7fffffff; }
    const int cand = t >> 3, j = t & 7;
    for (int ci = 0; ci < nc; ++ci) {
        int c = list[ci];
        const short* cb = bank + (size_t)c * CH32_SH;
        u16x8 h0 = *(const u16x8*)(cb + (size_t)(128 * j +  0 + cand) * 8);
        u16x8 h1 = *(const u16x8*)(cb + (size_t)(128 * j + 32 + cand) * 8);
        u16x8 h2 = *(const u16x8*)(cb + (size_t)(128 * j + 64 + cand) * 8);
        u16x8 h3 = *(const u16x8*)(cb + (size_t)(128 * j + 96 + cand) * 8);
        int d0 = j * 32;
        float acc = 0.f;
        #pragma unroll
        for (int d = 0; d < 8; ++d) {
            acc = fmaf(bf16f(h0[d]), qrow[d0 + d], acc);
            acc = fmaf(bf16f(h1[d]), qrow[d0 + 8 + d], acc);
            acc = fmaf(bf16f(h2[d]), qrow[d0 + 16 + d], acc);
            acc = fmaf(bf16f(h3[d]), qrow[d0 + 24 + d], acc);
        }
        acc += __shfl_down(acc, 4, 8);
        acc += __shfl_down(acc, 2, 8);
        acc += __shfl_down(acc, 1, 8);
        if (j == 0) insert6f(bv, bi, acc, c * CH32 + cand);
    }

    #pragma unroll
    for (int k = 0; k < 6; ++k) { sv[t][k] = bv[k]; si[t][k] = bi[k]; }
    __syncthreads();
    for (int w = 128; w >= 1; w >>= 1) {
        if (t < w) {
            float ov[6]; int oi[6];
            merge6(sv[t], si[t], sv[t + w], si[t + w], ov, oi);
            #pragma unroll
            for (int k = 0; k < 6; ++k) { sv[t][k] = ov[k]; si[t][k] = oi[k]; }
        }
        __syncthreads();
    }
    if (t == 0) {
        for (int k = 1; k < 6; ++k) out_idx[q * K_TOP + k - 1] = si[0][k];
    }
}

__global__ void k_loss(const float* __restrict__ softm, const float* __restrict__ score_bank,
                       const int* __restrict__ pos_of, const int* __restrict__ idx_near,
                       const int* __restrict__ idx_nn, const int* __restrict__ trg,
                       float* accp) {
    int b = blockIdx.x, c = threadIdx.x;   // 64 threads
    float p_bc = softm[b * C_DIM + c];
    float part = 0.f;
    for (int k = 0; k < K_TOP; ++k) {
        for (int j = 0; j < K_TOP; ++j) {
            int n = idx_nn[(b * K_TOP + k) * K_TOP + j];
            int p = pos_of[n];
            const float* srow = (p >= 0) ? (softm + (size_t)p * C_DIM)
                                         : (score_bank + (size_t)n * C_DIM);
            float s = srow[c];
            float v = s * (logf(s) - p_bc);
            for (int off = 32; off > 0; off >>= 1) v += __shfl_down(v, off, 64);
            if (c == 0) part += 0.1f * v;
        }
    }
    for (int k = 0; k < K_TOP; ++k) {
        int n = idx_near[b * K_TOP + k];
        int p = pos_of[n];
        const float* srow = (p >= 0) ? (softm + (size_t)p * C_DIM)
                                     : (score_bank + (size_t)n * C_DIM);
        float s = srow[c];
        float v = s * (logf(s) - p_bc);
        for (int off = 32; off > 0; off >>= 1) v += __shfl_down(v, off, 64);
        if (c == 0) {
            int m = 0;
            for (int j = 0; j < K_TOP; ++j)
                m += (idx_nn[(b * K_TOP + k) * K_TOP + j] == trg[b]) ? 1 : 0;
            float w = (m > 0) ? (float)m : 0.1f;
            part += w * v;
        }
    }
    if (c == 0) atomicAdd(accp, part * (1.0f / (float)B_SZ));
}

__global__ void k_final(const float* __restrict__ softm, const float* __restrict__ accp,
                        float* __restrict__ out) {
    int c = threadIdx.x;   // 64
    float m = 0.f;
    for (int b = 0; b < B_SZ; ++b) m += softm[b * C_DIM + c];
    m *= (1.0f / (float)B_SZ);
    float g = m * logf(m + 1e-5f);
    for (int off = 32; off > 0; off >>= 1) g += __shfl_down(g, off, 64);
    if (c == 0) out[0] = accp[0] + g;
}

extern "C" void kernel_launch(void* const* d_in, const int* in_sizes, int n_in,
                              void* d_out, int out_size, void* d_ws, size_t ws_size,
                              hipStream_t stream) {
    const float* features   = (const float*)d_in[0];
    const float* W          = (const float*)d_in[1];
    const float* bias       = (const float*)d_in[2];
    const float* fea_bank   = (const float*)d_in[3];
    const float* score_bank = (const float*)d_in[4];
    const int*   trg        = (const int*)d_in[5];
    float* out = (float*)d_out;

    char* ws = (char*)d_ws;
    size_t off = 0;
    auto alloc = [&](size_t bytes) -> void* {
        void* p = ws + off;
        off = (off + bytes + 255) & ~(size_t)255;
        return p;
    };
    short* bankbf   = (short*)alloc((size_t)NCH32 * CH32_SH * 2);            // 102.4 MB
    short* q1bf     = (short*)alloc((size_t)(B_SZ / 64) * QTILE_SH * 2);
    short* q2bf     = (short*)alloc((size_t)(B_SZ * K_TOP / 64) * QTILE_SH * 2);
    unsigned short* qplain1 = (unsigned short*)alloc((size_t)B_SZ * D_DIM * 2);
    unsigned short* qplain2 = (unsigned short*)alloc((size_t)B_SZ * K_TOP * D_DIM * 2);
    float* f_norm   = (float*)alloc((size_t)B_SZ * D_DIM * 4);
    float* softm    = (float*)alloc((size_t)B_SZ * C_DIM * 4);
    int*   pos_of   = (int*)alloc((size_t)N_CAND * 4);
    float* accp     = (float*)alloc(4);
    int*   idx_near = (int*)alloc((size_t)B_SZ * K_TOP * 4);
    int*   idx_nn   = (int*)alloc((size_t)B_SZ * K_TOP * K_TOP * 4);
    unsigned short* cmax1 = (unsigned short*)alloc((size_t)B_SZ * CMSTR * 2);
    unsigned short* cmax2 = (unsigned short*)alloc((size_t)B_SZ * K_TOP * CMSTR * 2);

    k_init<<<dim3((N_CAND + 255) / 256), dim3(256), 0, stream>>>(pos_of, accp);
    k_scatter<<<dim3(1), dim3(256), 0, stream>>>(trg, pos_of);
    k_prep<<<dim3(B_SZ), dim3(256), 0, stream>>>(features, W, bias, f_norm, softm);

    // pass-1 query tiles (also pads cmax1 row tails)
    k_permq<<<dim3(B_SZ / 64), dim3(256), 0, stream>>>(
        f_norm, fea_bank, nullptr, pos_of, q1bf, qplain1, cmax1);

    // FUSED bank convert + pass-1 distance max (3125 blocks, 2 chunks each)
    k_convert<<<dim3(NCH32 / 2), dim3(256), 0, stream>>>(
        fea_bank, f_norm, pos_of, q1bf, bankbf, cmax1);

    k_select<<<dim3(B_SZ), dim3(256), 0, stream>>>(cmax1, qplain1, bankbf, idx_near);

    // pass-2 query tiles (also pads cmax2 row tails)
    k_permq<<<dim3(B_SZ * K_TOP / 64), dim3(256), 0, stream>>>(
        f_norm, fea_bank, idx_near, pos_of, q2bf, qplain2, cmax2);

    // pass 2: 1280 queries = 5 block-qtiles of 256; 32-chunk jobs, XCD-grouped
    {
        int nqt = (B_SZ * K_TOP) / 256;           // 5
        int nsg = (S2 + 7) / 8;                   // 25
        dist_max<<<dim3(nsg * 8 * nqt), dim3(256), 0, stream>>>(
            q2bf, bankbf, cmax2, nqt, S2, NCHJ2);
    }
    k_select<<<dim3(B_SZ * K_TOP), dim3(256), 0, stream>>>(cmax2, qplain2, bankbf, idx_nn);

    k_loss<<<dim3(B_SZ), dim3(64), 0, stream>>>(softm, score_bank, pos_of, idx_near, idx_nn, trg, accp);
    k_final<<<dim3(1), dim3(64), 0, stream>>>(softm, accp, out);
}